// Round 3
// baseline (409.419 us; speedup 1.0000x reference)
//
#include <hip/hip_runtime.h>
#include <hip/hip_bf16.h>
#include <float.h>

// Problem constants
#define Q        4096
#define NTRAIN   50000
#define D        128
#define KNN      5

// Scoring tiling: block = 256 thr = 4 waves; tile 128 q x 64 t per subtile
#define NCHUNK   16
#define CHUNK    3125          // 50000 / 16 exact
#define SUBT     49            // ceil(3125/64); last subtile has 53 valid rows
#define NCAND    128           // 16 chunks * 8 candidates per query

typedef __attribute__((ext_vector_type(8))) short        short8;  // 8 bf16
typedef __attribute__((ext_vector_type(4))) float        f32x4;
typedef __attribute__((ext_vector_type(4))) unsigned int u32x4;

// ---- static sorted-insert (ascending, keeps smallest). All indices static. ----
#define INS_STEP(j, s_, i_, SS, SI) \
  { const bool b_ = (s_) < SS[(j)-1]; const bool c_ = (s_) < SS[(j)]; \
    SS[(j)] = b_ ? SS[(j)-1] : (c_ ? (s_) : SS[(j)]); \
    SI[(j)] = b_ ? SI[(j)-1] : (c_ ? (i_) : SI[(j)]); }
#define INS_LAST(s_, i_, SS, SI) \
  { const bool c_ = (s_) < SS[0]; SS[0] = c_ ? (s_) : SS[0]; SI[0] = c_ ? (i_) : SI[0]; }

#define INS8(s_, i_, SS, SI) do { if ((s_) < SS[7]) { \
  { const bool b_ = (s_) < SS[6]; SS[7] = b_ ? SS[6] : (s_); SI[7] = b_ ? SI[6] : (i_); } \
  INS_STEP(6, s_, i_, SS, SI) INS_STEP(5, s_, i_, SS, SI) INS_STEP(4, s_, i_, SS, SI) \
  INS_STEP(3, s_, i_, SS, SI) INS_STEP(2, s_, i_, SS, SI) INS_STEP(1, s_, i_, SS, SI) \
  INS_LAST(s_, i_, SS, SI) } } while (0)

#define INS5(s_, i_, SS, SI) do { if ((s_) < SS[4]) { \
  { const bool b_ = (s_) < SS[3]; SS[4] = b_ ? SS[3] : (s_); SI[4] = b_ ? SI[3] : (i_); } \
  INS_STEP(3, s_, i_, SS, SI) INS_STEP(2, s_, i_, SS, SI) INS_STEP(1, s_, i_, SS, SI) \
  INS_LAST(s_, i_, SS, SI) } } while (0)

// fp32 pair -> packed bf16 pair (RNE; maps to v_cvt_pk_bf16_f32)
__device__ __forceinline__ unsigned cvt_pk(float lo, float hi) {
  union { __hip_bfloat162 h; unsigned u; } v;
  float2 f; f.x = lo; f.y = hi;
  v.h = __float22bfloat162_rn(f);
  return v.u;
}

// 8 contiguous fp32 -> one bf16 granule (16 B)
__device__ __forceinline__ u32x4 cvt_granule(const float* __restrict__ p) {
  const float4 a = *(const float4*)p;
  const float4 b = *(const float4*)(p + 4);
  u32x4 r;
  r.x = cvt_pk(a.x, a.y); r.y = cvt_pk(a.z, a.w);
  r.z = cvt_pk(b.x, b.y); r.w = cvt_pk(b.z, b.w);
  return r;
}

// ---------------------------------------------------------------------------
// K0: tsq[n] = ||x_train[n]||^2 (fp32). 8 lanes per row, shfl reduce.
// ---------------------------------------------------------------------------
__global__ __launch_bounds__(256) void knn_tsq(const float* __restrict__ xt,
                                               float* __restrict__ tsq) {
  const int tid = threadIdx.x;
  const int row = blockIdx.x * 32 + (tid >> 3);
  if (row >= NTRAIN) return;          // whole 8-lane groups exit together
  const int l = tid & 7;
  float s = 0.0f;
  #pragma unroll
  for (int t = 0; t < 4; ++t) {
    const float4 v = *(const float4*)&xt[row * D + l * 4 + t * 32];
    s += v.x * v.x + v.y * v.y + v.z * v.z + v.w * v.w;
  }
  s += __shfl_xor(s, 1);
  s += __shfl_xor(s, 2);
  s += __shfl_xor(s, 4);
  if (l == 0) tsq[row] = s;
}

// ---------------------------------------------------------------------------
// K1: bf16 MFMA scoring + per-chunk top-8 candidate selection.
// Block: 256 thr = 4 waves (2 train-halves x 2 query-halves).
// Block tile: 128 queries x 64 train rows/subtile, K = 128 (full D).
// score = tsq[n] - 2 * <x_q, t_n>   (rank-equivalent to squared distance)
// fp32 inputs converted to bf16 in-register during staging (no global copies).
// Queries: resident register B-frags. Train: LDS, XOR-swizzled, double-buffered.
// ---------------------------------------------------------------------------
__global__ __launch_bounds__(256, 2) void knn_score(
    const float* __restrict__ x, const float* __restrict__ xt,
    const float* __restrict__ tsq, unsigned short* __restrict__ pi) {
  // smem: [0,32768) T double-buffer (2 x 64 rows x 128 bf16)
  //       after loop: [0,32768) Ms (8192 f32), [32768,49152) Mi (8192 u16)
  //       [49152,49664) tq_s[2][64]
  __shared__ __align__(16) unsigned char smem[49664];
  unsigned short* Tp   = (unsigned short*)smem;
  float*          Ms   = (float*)smem;
  unsigned short* Mi   = (unsigned short*)(smem + 32768);
  float*          tq_s = (float*)(smem + 49152);

  const int tid = threadIdx.x;
  const int l   = tid & 63;
  const int wid = tid >> 6;
  const int ti  = wid & 1;       // train half: rows ti*32..+31
  const int qw  = wid >> 1;      // query half: cols qw*64..+63
  const int q4  = l >> 4;        // 0..3
  const int l15 = l & 15;
  const int l7  = l & 7;

  // XCD-affine chunk swizzle: block n -> XCD n%8; chunks c and c+8 share an XCD,
  // so each XCD's L2 holds 2 chunk tiles (2 x 1.6 MB fp32 < 4 MB).
  const int n  = blockIdx.x;               // 0..511
  const int ch = n & 15;
  const int qb = n >> 4;                   // 0..31
  const int qbase = qb * 128;
  const int cbase = ch * CHUNK;

  // ---- resident query B-frags: B[k][col], col = l&15, k = ks*32 + q4*8 .. +8 ----
  short8 bq[4][4];
  #pragma unroll
  for (int cg = 0; cg < 4; ++cg) {
    const int qrow = qbase + qw * 64 + cg * 16 + l15;
    #pragma unroll
    for (int ks = 0; ks < 4; ++ks) {
      const u32x4 t = cvt_granule(&x[qrow * D + ks * 32 + q4 * 8]);
      bq[cg][ks] = __builtin_bit_cast(short8, t);
    }
  }

  // ---- staging constants: thread covers rows r*16 + (tid>>4), granule slot tid&15
  const int sp    = tid & 15;
  const int srow0 = tid >> 4;
  const int scg   = sp ^ (srow0 & 7);      // content granule (XOR swizzle)

  // ---- prologue: stage subtile 0 into buffer 0 ----
  {
    u32x4 g[4];
    #pragma unroll
    for (int r = 0; r < 4; ++r) {
      int grow = cbase + r * 16 + srow0;
      if (grow > NTRAIN - 1) grow = NTRAIN - 1;
      g[r] = cvt_granule(&xt[(size_t)grow * D + scg * 8]);
    }
    float tf = 0.f;
    if (tid < 64) tf = tsq[cbase + tid];   // st=0: all 64 rows valid
    #pragma unroll
    for (int r = 0; r < 4; ++r)
      *(u32x4*)&Tp[((r * 16 + srow0) * 16 + sp) * 8] = g[r];
    if (tid < 64) tq_s[tid] = tf;
    __syncthreads();
  }

  // ---- selection state: per lane, 4 queries (cg) x top-8 ----
  float ss[4][8]; int si[4][8];
  #pragma unroll
  for (int cg = 0; cg < 4; ++cg)
    #pragma unroll
    for (int m = 0; m < 8; ++m) { ss[cg][m] = FLT_MAX; si[cg][m] = 0; }

  for (int st = 0; st < SUBT; ++st) {
    const int cur   = st & 1;
    const int lbase = st * 64;
    const bool more = (st + 1 < SUBT);

    // T14: issue next-subtile global loads early (latency hides under MFMA)
    u32x4 g[4]; float tf = 1e30f;
    if (more) {
      #pragma unroll
      for (int r = 0; r < 4; ++r) {
        int grow = cbase + lbase + 64 + r * 16 + srow0;
        if (grow > NTRAIN - 1) grow = NTRAIN - 1;
        g[r] = cvt_granule(&xt[(size_t)grow * D + scg * 8]);
      }
      if (tid < 64) {
        const int lr = lbase + 64 + tid;
        tf = (lr < CHUNK) ? tsq[cbase + lr] : 1e30f;
      }
    }

    // ---- MFMA: acc[rg][cg] over K=128 (4 ksteps) ----
    f32x4 acc[2][4];
    #pragma unroll
    for (int rg = 0; rg < 2; ++rg)
      #pragma unroll
      for (int cg = 0; cg < 4; ++cg) acc[rg][cg] = (f32x4)0.f;

    #pragma unroll
    for (int rg = 0; rg < 2; ++rg) {
      const int rb = (ti * 32 + rg * 16 + l15) * 16;   // granule base of A row
      #pragma unroll
      for (int ks = 0; ks < 4; ++ks) {
        const int gx = (ks * 4 + q4) ^ l7;             // swizzled granule slot
        const short8 af = *(const short8*)&Tp[(size_t)cur * 8192 + (rb + gx) * 8];
        #pragma unroll
        for (int cg = 0; cg < 4; ++cg)
          acc[rg][cg] = __builtin_amdgcn_mfma_f32_16x16x32_bf16(
              af, bq[cg][ks], acc[rg][cg], 0, 0, 0);
      }
    }

    // ---- selection: score = tsq - 2*dot; per-cg min pre-filter, rare insert ----
    float t8[2][4];
    #pragma unroll
    for (int rg = 0; rg < 2; ++rg)
      #pragma unroll
      for (int r = 0; r < 4; ++r)
        t8[rg][r] = tq_s[cur * 64 + ti * 32 + rg * 16 + q4 * 4 + r];

    #pragma unroll
    for (int cg = 0; cg < 4; ++cg) {
      float sc8[8]; float mn = FLT_MAX;
      #pragma unroll
      for (int rg = 0; rg < 2; ++rg)
        #pragma unroll
        for (int r = 0; r < 4; ++r) {
          const float s = fmaf(-2.f, acc[rg][cg][r], t8[rg][r]);
          sc8[rg * 4 + r] = s;
          mn = fminf(mn, s);
        }
      if (mn < ss[cg][7]) {
        #pragma unroll
        for (int rg = 0; rg < 2; ++rg)
          #pragma unroll
          for (int r = 0; r < 4; ++r) {
            const int li = lbase + ti * 32 + rg * 16 + q4 * 4 + r;  // chunk-local
            INS8(sc8[rg * 4 + r], li, ss[cg], si[cg]);
          }
      }
    }

    __syncthreads();   // all reads of Tp[cur]/tq_s[cur] done
    if (more) {
      const int nb = cur ^ 1;
      #pragma unroll
      for (int r = 0; r < 4; ++r)
        *(u32x4*)&Tp[(size_t)nb * 8192 + ((r * 16 + srow0) * 16 + sp) * 8] = g[r];
      if (tid < 64) tq_s[nb * 64 + tid] = tf;
    }
    __syncthreads();   // next buffer visible
  }

  // ---- dump per-lane top-8 lists (8 lists per query) and reduce to top-8 ----
  #pragma unroll
  for (int cg = 0; cg < 4; ++cg) {
    const int q_loc = qw * 64 + cg * 16 + l15;
    const int base  = q_loc * 64 + (ti * 4 + q4) * 8;
    #pragma unroll
    for (int m = 0; m < 8; ++m) {
      const int slot = base + ((m + l15) & 7);         // bank-spread
      Ms[slot] = ss[cg][m];
      Mi[slot] = (unsigned short)si[cg][m];
    }
  }
  __syncthreads();

  if (tid < 128) {
    float SS[8]; int SI[8];
    #pragma unroll
    for (int m = 0; m < 8; ++m) { SS[m] = FLT_MAX; SI[m] = 0; }
    for (int e = 0; e < 64; ++e) {
      const int slot = tid * 64 + ((e + tid) & 63);    // bank-spread scan
      const float s  = Ms[slot];
      const int   i2 = (int)Mi[slot];
      INS8(s, i2, SS, SI);
    }
    #pragma unroll
    for (int m = 0; m < 8; ++m)
      pi[(qbase + tid) * NCAND + ch * 8 + m] = (unsigned short)SI[m];
  }
}

// ---------------------------------------------------------------------------
// K2: exact fp32 rescore of 128 candidates/query -> top-5 -> mean(y).
// Block = 128 threads, one candidate each. Grid = 4096 (one block/query).
// ---------------------------------------------------------------------------
__global__ __launch_bounds__(128) void knn_rescore(
    const float* __restrict__ x, const float* __restrict__ xt,
    const float* __restrict__ tsq, const unsigned short* __restrict__ pi,
    const float* __restrict__ y, float* __restrict__ out) {
  __shared__ float xs[D];
  __shared__ float csh[NCAND];
  __shared__ int   gix[NCAND];
  const int q = blockIdx.x, tid = threadIdx.x;
  xs[tid] = x[q * D + tid];
  __syncthreads();
  const int idx = (tid >> 3) * CHUNK + (int)pi[q * NCAND + tid];
  const float4* tp = (const float4*)(xt + (size_t)idx * D);
  float dot = 0.f;
  #pragma unroll 8
  for (int j = 0; j < 32; ++j) {
    const float4 tv = tp[j];
    const float4 xv = *(const float4*)&xs[j * 4];
    dot += tv.x * xv.x + tv.y * xv.y + tv.z * xv.z + tv.w * xv.w;
  }
  csh[tid] = tsq[idx] - 2.f * dot;
  gix[tid] = idx;
  __syncthreads();
  if (tid == 0) {
    float SS[5]; int SI[5];
    #pragma unroll
    for (int m = 0; m < 5; ++m) { SS[m] = FLT_MAX; SI[m] = 0; }
    for (int c = 0; c < NCAND; ++c) { INS5(csh[c], c, SS, SI); }
    float a = 0.f;
    #pragma unroll
    for (int m = 0; m < 5; ++m) a += y[gix[SI[m]]];
    out[q] = a * 0.2f;
  }
}

// ---------------------------------------------------------------------------
extern "C" void kernel_launch(void* const* d_in, const int* in_sizes, int n_in,
                              void* d_out, int out_size, void* d_ws, size_t ws_size,
                              hipStream_t stream) {
  (void)in_sizes; (void)n_in; (void)out_size; (void)ws_size;
  const float* x  = (const float*)d_in[0];   // [4096,128]
  const float* xt = (const float*)d_in[1];   // [50000,128]
  const float* y  = (const float*)d_in[2];   // [50000,1]
  float* out = (float*)d_out;                // [4096,1]

  // workspace layout (16B-aligned): total 1,248,576 B (was 16.1 MB in R2 —
  // suspected ws overflow corrupting harness pristine buffers)
  float*          tsq = (float*)d_ws;                        // 200,000 B
  unsigned short* pi  = (unsigned short*)((char*)d_ws + 200000);  // 1,048,576 B

  knn_tsq<<<dim3((NTRAIN + 31) / 32), dim3(256), 0, stream>>>(xt, tsq);
  knn_score<<<dim3(32 * NCHUNK), dim3(256), 0, stream>>>(x, xt, tsq, pi);
  knn_rescore<<<dim3(Q), dim3(128), 0, stream>>>(x, xt, tsq, pi, y, out);
}

// Round 6
// 322.875 us; speedup vs baseline: 1.2680x; 1.2680x over previous
//
#include <hip/hip_runtime.h>
#include <hip/hip_bf16.h>
#include <float.h>

// Problem constants
#define Q        4096
#define NTRAIN   50000
#define D        128
#define KNN      5

#define NCHUNK   16
#define CHUNK    3125          // 50000 / 16 exact
#define SUBT     49            // ceil(3125/64)
#define CAP      64            // per-query candidate buffer slots (= max appends/subtile)
#define NCAND    128           // 16 chunks * 8 candidates per query

typedef __attribute__((ext_vector_type(8))) short        short8;  // 8 bf16
typedef __attribute__((ext_vector_type(4))) float        f32x4;
typedef __attribute__((ext_vector_type(4))) unsigned int u32x4;

// ---- static sorted-insert (ascending, keeps smallest). All indices static. ----
#define INS_STEP(j, s_, i_, SS, SI) \
  { const bool b_ = (s_) < SS[(j)-1]; const bool c_ = (s_) < SS[(j)]; \
    SS[(j)] = b_ ? SS[(j)-1] : (c_ ? (s_) : SS[(j)]); \
    SI[(j)] = b_ ? SI[(j)-1] : (c_ ? (i_) : SI[(j)]); }
#define INS_LAST(s_, i_, SS, SI) \
  { const bool c_ = (s_) < SS[0]; SS[0] = c_ ? (s_) : SS[0]; SI[0] = c_ ? (i_) : SI[0]; }

#define INS8(s_, i_, SS, SI) do { if ((s_) < SS[7]) { \
  { const bool b_ = (s_) < SS[6]; SS[7] = b_ ? SS[6] : (s_); SI[7] = b_ ? SI[6] : (i_); } \
  INS_STEP(6, s_, i_, SS, SI) INS_STEP(5, s_, i_, SS, SI) INS_STEP(4, s_, i_, SS, SI) \
  INS_STEP(3, s_, i_, SS, SI) INS_STEP(2, s_, i_, SS, SI) INS_STEP(1, s_, i_, SS, SI) \
  INS_LAST(s_, i_, SS, SI) } } while (0)

#define INS5(s_, i_, SS, SI) do { if ((s_) < SS[4]) { \
  { const bool b_ = (s_) < SS[3]; SS[4] = b_ ? SS[3] : (s_); SI[4] = b_ ? SI[3] : (i_); } \
  INS_STEP(3, s_, i_, SS, SI) INS_STEP(2, s_, i_, SS, SI) INS_STEP(1, s_, i_, SS, SI) \
  INS_LAST(s_, i_, SS, SI) } } while (0)

// fp32 pair -> packed bf16 pair (RNE; maps to v_cvt_pk_bf16_f32)
__device__ __forceinline__ unsigned cvt_pk(float lo, float hi) {
  union { __hip_bfloat162 h; unsigned u; } v;
  float2 f; f.x = lo; f.y = hi;
  v.h = __float22bfloat162_rn(f);
  return v.u;
}

// 8 contiguous fp32 -> one bf16 granule (16 B)
__device__ __forceinline__ u32x4 cvt_granule(const float* __restrict__ p) {
  const float4 a = *(const float4*)p;
  const float4 b = *(const float4*)(p + 4);
  u32x4 r;
  r.x = cvt_pk(a.x, a.y); r.y = cvt_pk(a.z, a.w);
  r.z = cvt_pk(b.x, b.y); r.w = cvt_pk(b.z, b.w);
  return r;
}

// ---------------------------------------------------------------------------
// K0: tsq[n] = ||x_train[n]||^2 (fp32). 8 lanes per row, shfl reduce.
// ---------------------------------------------------------------------------
__global__ __launch_bounds__(256) void knn_tsq(const float* __restrict__ xt,
                                               float* __restrict__ tsq) {
  const int tid = threadIdx.x;
  const int row = blockIdx.x * 32 + (tid >> 3);
  if (row >= NTRAIN) return;
  const int l = tid & 7;
  float s = 0.0f;
  #pragma unroll
  for (int t = 0; t < 4; ++t) {
    const float4 v = *(const float4*)&xt[row * D + l * 4 + t * 32];
    s += v.x * v.x + v.y * v.y + v.z * v.z + v.w * v.w;
  }
  s += __shfl_xor(s, 1);
  s += __shfl_xor(s, 2);
  s += __shfl_xor(s, 4);
  if (l == 0) tsq[row] = s;
}

// ---------------------------------------------------------------------------
// K1: bf16 MFMA scoring + lazy-threshold candidate selection.
// Block: 256 thr = 4 waves; tile 128 queries x 64 train rows/subtile, K=128.
// Approx score s = qsq + tsq + 4 - 2*dot_bf16  (> 0 always, u32-order-safe).
// Selection: per-query LDS buffer (CAP=64) guarded by lazy theta (atomicMin of
// f32 bits); 2 owner lanes/query compact buffer -> register top-8 each subtile.
// Epilogue: merge to top-8/query; if WPSV also exact-fp32-rescore them
// (chunk L2-warm via XCD-affine mapping) and write scores; else indices only.
// ---------------------------------------------------------------------------
template <bool WPSV>
__global__ __launch_bounds__(256, 2) void knn_score(
    const float* __restrict__ x, const float* __restrict__ xt,
    const float* __restrict__ tsq, float* __restrict__ psv,
    unsigned short* __restrict__ pli) {
  __shared__ __align__(16) unsigned short Tp[64 * 128];   // 16 KB bf16 tile
  __shared__ __align__(16) float          SBuf[128][CAP]; // 32 KB cand scores
  __shared__ unsigned short               IBuf[128][CAP]; // 16 KB cand local idx
  __shared__ unsigned                     cnt[128];       // append counters
  __shared__ unsigned                     thu[128];       // theta (f32 bits)
  __shared__ float                        qsq_s[128];     // ||x_q||^2
  __shared__ float                        tq_s[64];       // tsq slice

  const int tid = threadIdx.x;
  const int l   = tid & 63;
  const int wid = tid >> 6;
  const int ti  = wid & 1;       // train half: rows ti*32..+31
  const int qw  = wid >> 1;      // query half: cols qw*64..+63
  const int q4  = l >> 4;        // 0..3
  const int l15 = l & 15;
  const int l7  = l & 7;

  // XCD-affine: block n -> XCD n%8; chunk = n&15 so chunks c,c+8 share an XCD
  // (2 x 1.6 MB fp32 < 4 MB L2) and all 32 blocks of a chunk sit on one XCD.
  const int n     = blockIdx.x;            // 0..511
  const int ch    = n & 15;
  const int qb    = n >> 4;                // 0..31
  const int qbase = qb * 128;
  const int cbase = ch * CHUNK;

  // ---- init control state ----
  if (tid < 128) { cnt[tid] = 0u; thu[tid] = 0x7F800000u; }  // theta = +inf

  // ---- qsq pre-pass: thread t computes ||x[qbase+t]||^2 ----
  if (tid < 128) {
    const float4* xr = (const float4*)&x[(qbase + tid) * D];
    float s = 0.f;
    #pragma unroll
    for (int j = 0; j < 32; ++j) {
      const float4 v = xr[j];
      s += v.x * v.x + v.y * v.y + v.z * v.z + v.w * v.w;
    }
    qsq_s[tid] = s;
  }

  // ---- resident query B-frags: col = l15, k = ks*32 + q4*8 .. +8 ----
  short8 bq[4][4];
  #pragma unroll
  for (int cg = 0; cg < 4; ++cg) {
    const int qrow = qbase + qw * 64 + cg * 16 + l15;
    #pragma unroll
    for (int ks = 0; ks < 4; ++ks) {
      const u32x4 t = cvt_granule(&x[qrow * D + ks * 32 + q4 * 8]);
      bq[cg][ks] = __builtin_bit_cast(short8, t);
    }
  }

  // ---- staging constants: rows r*16 + (tid>>4), granule slot tid&15 ----
  const int sp    = tid & 15;
  const int srow0 = tid >> 4;
  const int scg   = sp ^ (srow0 & 7);      // XOR-swizzled content granule

  // ---- prologue: stage subtile 0 ----
  {
    u32x4 g[4];
    #pragma unroll
    for (int r = 0; r < 4; ++r) {
      const int grow = cbase + r * 16 + srow0;         // always < NTRAIN
      g[r] = cvt_granule(&xt[(size_t)grow * D + scg * 8]);
    }
    float tf = 0.f;
    if (tid < 64) tf = tsq[cbase + tid];
    #pragma unroll
    for (int r = 0; r < 4; ++r)
      *(u32x4*)&Tp[((r * 16 + srow0) * 16 + sp) * 8] = g[r];
    if (tid < 64) tq_s[tid] = tf;
  }
  __syncthreads();

  // per-lane query-sq (+4 bias keeps s > 0 despite bf16 dot error)
  float q4b[4];
  #pragma unroll
  for (int cg = 0; cg < 4; ++cg) q4b[cg] = qsq_s[qw * 64 + cg * 16 + l15] + 4.0f;

  // owner state: 2 owners per query (same wave -> lockstep ordering)
  const int cq   = tid >> 1;
  const int half = tid & 1;
  float oss[8]; int osi[8];
  #pragma unroll
  for (int m = 0; m < 8; ++m) { oss[m] = FLT_MAX; osi[m] = 0; }

  for (int st = 0; st < SUBT; ++st) {
    const int lbase = st * 64;
    const bool more = (st + 1 < SUBT);

    // T14: issue next-subtile global loads early (hide HBM/L2 under MFMA)
    u32x4 g[4]; float tf = 1e30f;
    if (more) {
      #pragma unroll
      for (int r = 0; r < 4; ++r) {
        int grow = cbase + lbase + 64 + r * 16 + srow0;
        if (grow > NTRAIN - 1) grow = NTRAIN - 1;
        g[r] = cvt_granule(&xt[(size_t)grow * D + scg * 8]);
      }
      if (tid < 64) {
        const int lr = lbase + 64 + tid;
        tf = (lr < CHUNK) ? tsq[cbase + lr] : 1e30f;   // kill pads/interlopers
      }
    }

    // ---- MFMA: acc[rg][cg] over K=128 ----
    f32x4 acc[2][4];
    #pragma unroll
    for (int rg = 0; rg < 2; ++rg)
      #pragma unroll
      for (int cg = 0; cg < 4; ++cg) acc[rg][cg] = (f32x4)0.f;

    #pragma unroll
    for (int rg = 0; rg < 2; ++rg) {
      const int rb = (ti * 32 + rg * 16 + l15) * 16;
      #pragma unroll
      for (int ks = 0; ks < 4; ++ks) {
        const int gx = (ks * 4 + q4) ^ l7;
        const short8 af = *(const short8*)&Tp[(rb + gx) * 8];
        #pragma unroll
        for (int cg = 0; cg < 4; ++cg)
          acc[rg][cg] = __builtin_amdgcn_mfma_f32_16x16x32_bf16(
              af, bq[cg][ks], acc[rg][cg], 0, 0, 0);
      }
    }

    // ---- selection: min8 pre-filter + threshold + rare atomic append ----
    const float4 t80 = *(const float4*)&tq_s[ti * 32 + q4 * 4];
    const float4 t81 = *(const float4*)&tq_s[ti * 32 + 16 + q4 * 4];
    const float tqa[8] = {t80.x, t80.y, t80.z, t80.w, t81.x, t81.y, t81.z, t81.w};

    #pragma unroll
    for (int cg = 0; cg < 4; ++cg) {
      const int qloc = qw * 64 + cg * 16 + l15;
      const float thf = __uint_as_float(thu[qloc]);   // stale = permissive = safe
      const float bb  = q4b[cg];
      float sc8[8]; float mn = FLT_MAX;
      #pragma unroll
      for (int rg = 0; rg < 2; ++rg)
        #pragma unroll
        for (int r = 0; r < 4; ++r) {
          const float s = fmaf(-2.f, acc[rg][cg][r], tqa[rg * 4 + r] + bb);
          sc8[rg * 4 + r] = s;
          mn = fminf(mn, s);
        }
      if (mn < thf) {                                  // rare after subtile 0
        #pragma unroll
        for (int rg = 0; rg < 2; ++rg)
          #pragma unroll
          for (int r = 0; r < 4; ++r) {
            const float s = sc8[rg * 4 + r];
            if (s < thf) {
              const unsigned pos = atomicAdd(&cnt[qloc], 1u);  // pos < CAP always
              SBuf[qloc][pos] = s;
              IBuf[qloc][pos] =
                  (unsigned short)(lbase + ti * 32 + rg * 16 + q4 * 4 + r);
            }
          }
      }
    }

    __syncthreads();   // B1: appends + Tp reads done

    // stage next subtile (Tp region disjoint from compaction arrays)
    if (more) {
      #pragma unroll
      for (int r = 0; r < 4; ++r)
        *(u32x4*)&Tp[((r * 16 + srow0) * 16 + sp) * 8] = g[r];
      if (tid < 64) tq_s[tid] = tf;
    }

    // compaction: both owners of query cq are lanes 2cq,2cq+1 (same wave):
    // the cnt read issues before half0's reset store (wave lockstep).
    {
      unsigned c = cnt[cq]; if (c > CAP) c = CAP;
      for (unsigned e = (unsigned)half; e < c; e += 2) {
        const float s  = SBuf[cq][e];
        const int   i2 = (int)IBuf[cq][e];
        INS8(s, i2, oss, osi);
      }
      atomicMin(&thu[cq], __float_as_uint(oss[7]));
      if (half == 0) cnt[cq] = 0;
    }

    __syncthreads();   // B2: theta/cnt/Tp ready for next subtile
  }

  // ---- merge the two owner lists -> top-8 local indices per query ----
  #pragma unroll
  for (int m = 0; m < 8; ++m) {
    SBuf[cq][half * 8 + m] = oss[m];
    IBuf[cq][half * 8 + m] = (unsigned short)osi[m];
  }
  __syncthreads();

  if (tid < 128) {
    int ia = 0, ib = 0;
    #pragma unroll
    for (int m = 0; m < 8; ++m) {
      const float sa = SBuf[tid][ia];
      const float sb = SBuf[tid][8 + ib];
      const bool ta = sa <= sb;
      IBuf[tid][16 + m] = ta ? IBuf[tid][ia] : IBuf[tid][8 + ib];
      ia += ta ? 1 : 0; ib += ta ? 0 : 1;
    }
  }
  __syncthreads();

  if constexpr (WPSV) {
    // ---- exact fp32 rescore: thread -> query cq, candidates half*4..+3 ----
    const int qx = qbase + cq;
    const float* xrow = &x[qx * D];
    int li4[4];
    #pragma unroll
    for (int j = 0; j < 4; ++j) li4[j] = (int)IBuf[cq][16 + half * 4 + j];
    float dot4[4] = {0.f, 0.f, 0.f, 0.f};
    #pragma unroll 8
    for (int kk = 0; kk < 32; ++kk) {
      const float4 xv = *(const float4*)&xrow[kk * 4];
      #pragma unroll
      for (int j = 0; j < 4; ++j) {
        const float4 tv = *(const float4*)&xt[(size_t)(cbase + li4[j]) * D + kk * 4];
        dot4[j] = fmaf(xv.x, tv.x, fmaf(xv.y, tv.y,
                  fmaf(xv.z, tv.z, fmaf(xv.w, tv.w, dot4[j]))));
      }
    }
    #pragma unroll
    for (int j = 0; j < 4; ++j) {
      const int gi   = cbase + li4[j];
      const int slot = qx * NCAND + ch * 8 + half * 4 + j;
      psv[slot] = tsq[gi] - 2.f * dot4[j];   // exact rank key (xsq common/query)
      pli[slot] = (unsigned short)li4[j];
    }
  } else {
    // ---- indices only (compact-ws fallback path) ----
    if (tid < 128) {
      #pragma unroll
      for (int m = 0; m < 8; ++m)
        pli[(qbase + tid) * NCAND + ch * 8 + m] = IBuf[tid][16 + m];
    }
  }
}

// ---------------------------------------------------------------------------
// K2a (path A): per query, top-5 of 128 exact-scored candidates -> mean(y).
// ---------------------------------------------------------------------------
__global__ __launch_bounds__(256) void knn_final(
    const float* __restrict__ psv, const unsigned short* __restrict__ pli,
    const float* __restrict__ y, float* __restrict__ out) {
  const int q = blockIdx.x * 256 + threadIdx.x;
  if (q >= Q) return;
  float SS[5]; int SI[5];
  #pragma unroll
  for (int m = 0; m < 5; ++m) { SS[m] = FLT_MAX; SI[m] = 0; }
  for (int c = 0; c < NCAND; ++c) {
    const float s = psv[q * NCAND + c];
    INS5(s, c, SS, SI);
  }
  float a = 0.f;
  #pragma unroll
  for (int m = 0; m < 5; ++m) {
    const int c  = SI[m];
    const int gi = (c >> 3) * CHUNK + (int)pli[q * NCAND + c];
    a += y[gi];
  }
  out[q] = a * 0.2f;
}

// ---------------------------------------------------------------------------
// K2b (path B): exact fp32 rescore of 128 candidates/query -> top-5 -> mean(y).
// One block (128 thr) per query; R3-proven structure.
// ---------------------------------------------------------------------------
__global__ __launch_bounds__(128) void knn_rescore_full(
    const float* __restrict__ x, const float* __restrict__ xt,
    const float* __restrict__ tsq, const unsigned short* __restrict__ pli,
    const float* __restrict__ y, float* __restrict__ out) {
  __shared__ float xs[D];
  __shared__ float csh[NCAND];
  __shared__ int   gix[NCAND];
  const int q = blockIdx.x, tid = threadIdx.x;
  xs[tid] = x[q * D + tid];
  __syncthreads();
  const int idx = (tid >> 3) * CHUNK + (int)pli[q * NCAND + tid];
  const float4* tp = (const float4*)(xt + (size_t)idx * D);
  float dot = 0.f;
  #pragma unroll 8
  for (int j = 0; j < 32; ++j) {
    const float4 tv = tp[j];
    const float4 xv = *(const float4*)&xs[j * 4];
    dot += tv.x * xv.x + tv.y * xv.y + tv.z * xv.z + tv.w * xv.w;
  }
  csh[tid] = tsq[idx] - 2.f * dot;
  gix[tid] = idx;
  __syncthreads();
  if (tid == 0) {
    float SS[5]; int SI[5];
    #pragma unroll
    for (int m = 0; m < 5; ++m) { SS[m] = FLT_MAX; SI[m] = 0; }
    for (int c = 0; c < NCAND; ++c) { INS5(csh[c], c, SS, SI); }
    float a = 0.f;
    #pragma unroll
    for (int m = 0; m < 5; ++m) a += y[gix[SI[m]]];
    out[q] = a * 0.2f;
  }
}

// ---------------------------------------------------------------------------
extern "C" void kernel_launch(void* const* d_in, const int* in_sizes, int n_in,
                              void* d_out, int out_size, void* d_ws, size_t ws_size,
                              hipStream_t stream) {
  (void)in_sizes; (void)n_in; (void)out_size;
  const float* x  = (const float*)d_in[0];   // [4096,128]
  const float* xt = (const float*)d_in[1];   // [50000,128]
  const float* y  = (const float*)d_in[2];   // [50000,1]
  float* out = (float*)d_out;                // [4096,1]

  // Path A layout: tsq 200,704 | psv 2,097,152 | pli 1,048,576  = 3,346,432 B
  // Path B layout: tsq 200,704 | pli 1,048,576                  = 1,249,280 B
  float*          tsq = (float*)d_ws;
  const bool fullws = ws_size >= (size_t)3346432;

  knn_tsq<<<dim3((NTRAIN + 31) / 32), dim3(256), 0, stream>>>(xt, tsq);

  if (fullws) {
    float*          psv = (float*)((char*)d_ws + 200704);
    unsigned short* pli = (unsigned short*)((char*)d_ws + 200704 + 2097152);
    knn_score<true><<<dim3(512), dim3(256), 0, stream>>>(x, xt, tsq, psv, pli);
    knn_final<<<dim3(Q / 256), dim3(256), 0, stream>>>(psv, pli, y, out);
  } else {
    unsigned short* pli = (unsigned short*)((char*)d_ws + 200704);
    knn_score<false><<<dim3(512), dim3(256), 0, stream>>>(x, xt, tsq,
                                                          (float*)nullptr, pli);
    knn_rescore_full<<<dim3(Q), dim3(128), 0, stream>>>(x, xt, tsq, pli, y, out);
  }
}

// Round 7
// 243.072 us; speedup vs baseline: 1.6844x; 1.3283x over previous
//
#include <hip/hip_runtime.h>
#include <hip/hip_bf16.h>
#include <float.h>

// Problem constants
#define Q        4096
#define NTRAIN   50000
#define D        128
#define KNN      5

#define NCHUNK   16
#define CHUNK    3125          // 50000 / 16 exact
#define SUBT     49            // ceil(3125/64)
#define CAP      64            // per-query candidate slots (= max appends/subtile)
#define NCAND    128           // 16 chunks * 8 candidates per query

typedef __attribute__((ext_vector_type(8))) short        short8;  // 8 bf16
typedef __attribute__((ext_vector_type(4))) float        f32x4;
typedef __attribute__((ext_vector_type(4))) unsigned int u32x4;

// ---- static sorted-insert on packed u32 (ascending, keeps 8 smallest) ----
#define U_STEP(j, v_, SS) \
  { const bool b_ = (v_) < SS[(j)-1]; const bool c_ = (v_) < SS[(j)]; \
    SS[(j)] = b_ ? SS[(j)-1] : (c_ ? (v_) : SS[(j)]); }
#define INS8U(v_, SS) do { if ((v_) < SS[7]) { \
  { const bool b_ = (v_) < SS[6]; SS[7] = b_ ? SS[6] : (v_); } \
  U_STEP(6, v_, SS) U_STEP(5, v_, SS) U_STEP(4, v_, SS) \
  U_STEP(3, v_, SS) U_STEP(2, v_, SS) U_STEP(1, v_, SS) \
  { if ((v_) < SS[0]) SS[0] = (v_); } } } while (0)

// fp32 pair -> packed bf16 pair (v_cvt_pk_bf16_f32)
__device__ __forceinline__ unsigned cvt_pk(float lo, float hi) {
  union { __hip_bfloat162 h; unsigned u; } v;
  float2 f; f.x = lo; f.y = hi;
  v.h = __float22bfloat162_rn(f);
  return v.u;
}
// 8 contiguous fp32 -> one bf16 granule (16 B)
__device__ __forceinline__ u32x4 cvt_granule(const float* __restrict__ p) {
  const float4 a = *(const float4*)p;
  const float4 b = *(const float4*)(p + 4);
  u32x4 r;
  r.x = cvt_pk(a.x, a.y); r.y = cvt_pk(a.z, a.w);
  r.z = cvt_pk(b.x, b.y); r.w = cvt_pk(b.z, b.w);
  return r;
}

// ---------------------------------------------------------------------------
// K0: tsq[n] = ||x_train[n]||^2 (fp32). 8 lanes per row, shfl reduce.
// ---------------------------------------------------------------------------
__global__ __launch_bounds__(256) void knn_tsq(const float* __restrict__ xt,
                                               float* __restrict__ tsq) {
  const int tid = threadIdx.x;
  const int row = blockIdx.x * 32 + (tid >> 3);
  if (row >= NTRAIN) return;
  const int l = tid & 7;
  float s = 0.0f;
  #pragma unroll
  for (int t = 0; t < 4; ++t) {
    const float4 v = *(const float4*)&xt[row * D + l * 4 + t * 32];
    s += v.x * v.x + v.y * v.y + v.z * v.z + v.w * v.w;
  }
  s += __shfl_xor(s, 1);
  s += __shfl_xor(s, 2);
  s += __shfl_xor(s, 4);
  if (l == 0) tsq[row] = s;
}

// ---------------------------------------------------------------------------
// K1: bf16 MFMA scoring + lazy-threshold selection (packed-u32, deterministic).
// Block: 512 thr = 8 waves (ti in {0,1} row-half x qw in 0..3 query-quarter).
// Tile: 128 queries x 64 train rows/subtile, K=128.
// packed p = (f32bits(score) & ~0xFFF) | local_idx  (score > 0, idx < 4096)
//   -> unsigned order == quantized-score order, idx tiebreak => deterministic.
// theta[q] (LDS u32, atomicMin) guards appends; seeded at st=0 by a provable
// 8-distinct-element upper bound (per-lane pair-minima + shfl_xor max-reduce).
// 4 owner lanes/query compact the CAP=64 LDS buffer into register top-8s.
// ---------------------------------------------------------------------------
__global__ __launch_bounds__(512, 4) void knn_score(
    const float* __restrict__ x, const float* __restrict__ xt,
    const float* __restrict__ tsq, unsigned short* __restrict__ pli) {
  __shared__ __align__(16) unsigned short Tp[64 * 128];     // 16 KB bf16 tile
  __shared__ unsigned SBuf[128][CAP + 1];                   // 33.3 KB (pad->bank-spread)
  __shared__ unsigned cnt[128];
  __shared__ unsigned thu[128];                             // theta (packed bits)
  __shared__ float    qsq_s[128];
  __shared__ float    tq_s[64];

  const int tid = threadIdx.x;
  const int l   = tid & 63;
  const int wid = tid >> 6;
  const int ti  = wid & 1;        // train half: rows ti*32..+31
  const int qw  = wid >> 1;       // query quarter: cols qw*32..+31
  const int q4  = l >> 4;
  const int l15 = l & 15;
  const int l7  = l & 7;

  // XCD-affine: block n -> XCD n%8; chunks c,c+8 share an XCD L2.
  const int n     = blockIdx.x;             // 0..511
  const int ch    = n & 15;
  const int qb    = n >> 4;
  const int qbase = qb * 128;
  const int cbase = ch * CHUNK;

  if (tid < 128) { cnt[tid] = 0u; thu[tid] = 0xFFFFFFFFu; }

  // qsq pre-pass
  if (tid < 128) {
    const float4* xr = (const float4*)&x[(qbase + tid) * D];
    float s = 0.f;
    #pragma unroll
    for (int j = 0; j < 32; ++j) {
      const float4 v = xr[j];
      s += v.x * v.x + v.y * v.y + v.z * v.z + v.w * v.w;
    }
    qsq_s[tid] = s;
  }

  // resident query B-frags: col = l15, k = ks*32 + q4*8 .. +8
  short8 bq[2][4];
  #pragma unroll
  for (int cg = 0; cg < 2; ++cg) {
    const int qrow = qbase + qw * 32 + cg * 16 + l15;
    #pragma unroll
    for (int ks = 0; ks < 4; ++ks) {
      const u32x4 t = cvt_granule(&x[qrow * D + ks * 32 + q4 * 8]);
      bq[cg][ks] = __builtin_bit_cast(short8, t);
    }
  }

  // staging: thread covers rows {srow0, srow0+32}, granule slot sp
  const int sp    = tid & 15;
  const int srow0 = tid >> 4;               // 0..31
  const int scg   = sp ^ (srow0 & 7);       // XOR-swizzled content granule

  // prologue: stage subtile 0
  {
    u32x4 g[2];
    #pragma unroll
    for (int r = 0; r < 2; ++r) {
      const int grow = cbase + srow0 + r * 32;           // < NTRAIN
      g[r] = cvt_granule(&xt[(size_t)grow * D + scg * 8]);
    }
    float tf = 0.f;
    if (tid < 64) tf = tsq[cbase + tid];
    #pragma unroll
    for (int r = 0; r < 2; ++r)
      *(u32x4*)&Tp[((srow0 + r * 32) * 16 + sp) * 8] = g[r];
    if (tid < 64) tq_s[tid] = tf;
  }
  __syncthreads();

  float q2b[2];
  #pragma unroll
  for (int cg = 0; cg < 2; ++cg) q2b[cg] = qsq_s[qw * 32 + cg * 16 + l15] + 4.0f;

  // owners: 4 per query (lanes 4cq..4cq+3, same wave -> lockstep cnt read/reset)
  const int cq = tid >> 2;
  const int h4 = tid & 3;
  unsigned oss[8];
  #pragma unroll
  for (int m = 0; m < 8; ++m) oss[m] = 0xFFFFFFFFu;
  unsigned pub7 = 0xFFFFFFFFu;    // last published 8th

  for (int st = 0; st < SUBT; ++st) {
    const int lbase = st * 64;
    const bool more = (st + 1 < SUBT);

    // T14: issue next-subtile loads early
    u32x4 g[2]; float tf = 1e30f;
    if (more) {
      #pragma unroll
      for (int r = 0; r < 2; ++r) {
        int grow = cbase + lbase + 64 + srow0 + r * 32;
        if (grow > NTRAIN - 1) grow = NTRAIN - 1;
        g[r] = cvt_granule(&xt[(size_t)grow * D + scg * 8]);
      }
      if (tid < 64) {
        const int lr = lbase + 64 + tid;
        tf = (lr < CHUNK) ? tsq[cbase + lr] : 1e30f;     // kill pads
      }
    }

    // MFMA over K=128
    f32x4 acc[2][2];
    #pragma unroll
    for (int rg = 0; rg < 2; ++rg)
      #pragma unroll
      for (int cg = 0; cg < 2; ++cg) acc[rg][cg] = (f32x4)0.f;

    #pragma unroll
    for (int rg = 0; rg < 2; ++rg) {
      const int rb = (ti * 32 + rg * 16 + l15) * 16;
      #pragma unroll
      for (int ks = 0; ks < 4; ++ks) {
        const int gx = (ks * 4 + q4) ^ l7;
        const short8 af = *(const short8*)&Tp[(rb + gx) * 8];
        #pragma unroll
        for (int cg = 0; cg < 2; ++cg)
          acc[rg][cg] = __builtin_amdgcn_mfma_f32_16x16x32_bf16(
              af, bq[cg][ks], acc[rg][cg], 0, 0, 0);
      }
    }

    // selection
    float tqa[8];
    #pragma unroll
    for (int rg = 0; rg < 2; ++rg) {
      const float4 t4 = *(const float4*)&tq_s[ti * 32 + rg * 16 + q4 * 4];
      tqa[rg * 4 + 0] = t4.x; tqa[rg * 4 + 1] = t4.y;
      tqa[rg * 4 + 2] = t4.z; tqa[rg * 4 + 3] = t4.w;
    }

    #pragma unroll
    for (int cg = 0; cg < 2; ++cg) {
      const int qloc = qw * 32 + cg * 16 + l15;
      const float bb = q2b[cg];
      float sc[8];
      #pragma unroll
      for (int rg = 0; rg < 2; ++rg)
        #pragma unroll
        for (int r = 0; r < 4; ++r)
          sc[rg * 4 + r] = fmaf(-2.f, acc[rg][cg][r], tqa[rg * 4 + r] + bb);

      if (st == 0) {
        // seed theta: max of 8 distinct per-lane pair-minima (>= 8th smallest)
        const float a_ = fminf(fminf(sc[0], sc[1]), fminf(sc[2], sc[3]));
        const float b_ = fminf(fminf(sc[4], sc[5]), fminf(sc[6], sc[7]));
        float mx = fmaxf(a_, b_);
        mx = fmaxf(mx, __shfl_xor(mx, 16));
        mx = fmaxf(mx, __shfl_xor(mx, 32));
        const unsigned pb = (__float_as_uint(mx) & 0xFFFFF000u) | 0xFFFu;
        atomicMin(&thu[qloc], pb);
      }

      const unsigned thp = thu[qloc];                  // stale = permissive = safe
      const float thf = __uint_as_float(thp | 0xFFFu); // permissive float bound
      float mn = sc[0];
      #pragma unroll
      for (int m = 1; m < 8; ++m) mn = fminf(mn, sc[m]);

      if (mn <= thf) {                                  // rare after st=0
        #pragma unroll
        for (int rg = 0; rg < 2; ++rg)
          #pragma unroll
          for (int r = 0; r < 4; ++r) {
            const unsigned li = (unsigned)(lbase + ti * 32 + rg * 16 + q4 * 4 + r);
            const unsigned p  =
                (__float_as_uint(sc[rg * 4 + r]) & 0xFFFFF000u) | li;
            if (p < thp) {
              const unsigned pos = atomicAdd(&cnt[qloc], 1u);  // < CAP always
              SBuf[qloc][pos] = p;
            }
          }
      }
    }

    __syncthreads();   // B1: appends + Tp reads done

    if (more) {
      #pragma unroll
      for (int r = 0; r < 2; ++r)
        *(u32x4*)&Tp[((srow0 + r * 32) * 16 + sp) * 8] = g[r];
      if (tid < 64) tq_s[tid] = tf;
    }

    // compaction (4 owners/query, same wave)
    {
      unsigned c = cnt[cq]; if (c > CAP) c = CAP;
      for (unsigned e = (unsigned)h4; e < c; e += 4) {
        const unsigned v = SBuf[cq][e];
        INS8U(v, oss);
      }
      if (oss[7] < pub7) { pub7 = oss[7]; atomicMin(&thu[cq], pub7); }
      if (h4 == 0) cnt[cq] = 0u;
    }

    __syncthreads();   // B2: theta/cnt/Tp ready
  }

  // merge 4 owner lists -> top-8 per query -> write local indices
  #pragma unroll
  for (int m = 0; m < 8; ++m) SBuf[cq][h4 * 8 + m] = oss[m];
  __syncthreads();

  if (tid < 128) {
    unsigned best[8];
    #pragma unroll
    for (int m = 0; m < 8; ++m) best[m] = 0xFFFFFFFFu;
    #pragma unroll 4
    for (int e = 0; e < 32; ++e) {
      const unsigned v = SBuf[tid][e];
      INS8U(v, best);
    }
    #pragma unroll
    for (int m = 0; m < 8; ++m)
      pli[(qbase + tid) * NCAND + ch * 8 + m] = (unsigned short)(best[m] & 0xFFFu);
  }
}

// ---------------------------------------------------------------------------
// K2: exact fp32 rescore of 128 candidates/query -> top-5 -> mean(y).
// Block 256 = 4 waves; 8-lane groups own candidate rows (coalesced 128B reads);
// shfl-reduced dots; wave-parallel sorted-5 merge (merge-path identity).
// ---------------------------------------------------------------------------
__global__ __launch_bounds__(256) void knn_rescore(
    const float* __restrict__ x, const float* __restrict__ xt,
    const float* __restrict__ tsq, const unsigned short* __restrict__ pli,
    const float* __restrict__ y, float* __restrict__ out) {
  __shared__ float xs[D];
  __shared__ float csh[NCAND];
  __shared__ int   gsh[NCAND];

  const int q   = blockIdx.x;
  const int tid = threadIdx.x;
  const int w   = tid >> 6;
  const int l   = tid & 63;
  const int g   = l >> 3;       // group 0..7
  const int ls  = l & 7;        // lane-in-group

  if (tid < 32) ((float4*)xs)[tid] = ((const float4*)&x[(size_t)q * D])[tid];
  __syncthreads();

  #pragma unroll
  for (int p = 0; p < 4; ++p) {
    const int c  = p * 32 + w * 8 + g;
    const int li = (int)pli[q * NCAND + c];
    const int gi = (c >> 3) * CHUNK + li;
    float dot = 0.f;
    #pragma unroll
    for (int it = 0; it < 4; ++it) {
      const int off = it * 32 + ls * 4;
      const float4 tv = *(const float4*)&xt[(size_t)gi * D + off];
      const float4 xv = *(const float4*)&xs[off];
      dot = fmaf(tv.x, xv.x, fmaf(tv.y, xv.y,
            fmaf(tv.z, xv.z, fmaf(tv.w, xv.w, dot))));
    }
    dot += __shfl_xor(dot, 1);
    dot += __shfl_xor(dot, 2);
    dot += __shfl_xor(dot, 4);
    if (ls == 0) { csh[c] = tsq[gi] - 2.f * dot; gsh[c] = gi; }
  }
  __syncthreads();

  // wave 0: parallel top-5 (exact scores; FLT_MAX padding)
  if (tid < 64) {
    float s0 = csh[tid], s1 = csh[tid + 64];
    int   i0 = gsh[tid], i1 = gsh[tid + 64];
    float av0, av1, av2, av3, av4; int ai0, ai1, ai2, ai3, ai4;
    const bool o = s0 <= s1;
    av0 = o ? s0 : s1; ai0 = o ? i0 : i1;
    av1 = o ? s1 : s0; ai1 = o ? i1 : i0;
    av2 = FLT_MAX; av3 = FLT_MAX; av4 = FLT_MAX; ai2 = 0; ai3 = 0; ai4 = 0;

    #define PMAXV(as, ai_, bs, bi_, rs, ri_) \
      { const bool t_ = (as) >= (bs); rs = t_ ? (as) : (bs); ri_ = t_ ? (ai_) : (bi_); }
    #define PMINA(bs, bi_, rs, ri_) \
      { const bool t_ = (bs) < (rs); rs = t_ ? (bs) : (rs); ri_ = t_ ? (bi_) : (ri_); }

    #pragma unroll
    for (int lvl = 1; lvl < 64; lvl <<= 1) {
      float bv0 = __shfl_xor(av0, lvl), bv1 = __shfl_xor(av1, lvl),
            bv2 = __shfl_xor(av2, lvl), bv3 = __shfl_xor(av3, lvl),
            bv4 = __shfl_xor(av4, lvl);
      int   bi0 = __shfl_xor(ai0, lvl), bi1 = __shfl_xor(ai1, lvl),
            bi2 = __shfl_xor(ai2, lvl), bi3 = __shfl_xor(ai3, lvl),
            bi4 = __shfl_xor(ai4, lvl);
      float c0, c1, c2, c3, c4, t; int ci0, ci1, ci2, ci3, ci4, ti_;
      // c0 = min(a0,b0)
      { const bool t_ = av0 <= bv0; c0 = t_ ? av0 : bv0; ci0 = t_ ? ai0 : bi0; }
      // c1 = min(a1, max(a0,b0), b1)
      PMAXV(av0, ai0, bv0, bi0, t, ti_);
      { const bool t_ = av1 <= bv1; c1 = t_ ? av1 : bv1; ci1 = t_ ? ai1 : bi1; }
      PMINA(t, ti_, c1, ci1);
      // c2 = min(a2, max(a1,b0), max(a0,b1), b2)
      { const bool t_ = av2 <= bv2; c2 = t_ ? av2 : bv2; ci2 = t_ ? ai2 : bi2; }
      PMAXV(av1, ai1, bv0, bi0, t, ti_); PMINA(t, ti_, c2, ci2);
      PMAXV(av0, ai0, bv1, bi1, t, ti_); PMINA(t, ti_, c2, ci2);
      // c3 = min(a3, max(a2,b0), max(a1,b1), max(a0,b2), b3)
      { const bool t_ = av3 <= bv3; c3 = t_ ? av3 : bv3; ci3 = t_ ? ai3 : bi3; }
      PMAXV(av2, ai2, bv0, bi0, t, ti_); PMINA(t, ti_, c3, ci3);
      PMAXV(av1, ai1, bv1, bi1, t, ti_); PMINA(t, ti_, c3, ci3);
      PMAXV(av0, ai0, bv2, bi2, t, ti_); PMINA(t, ti_, c3, ci3);
      // c4 = min(a4, max(a3,b0), max(a2,b1), max(a1,b2), max(a0,b3), b4)
      { const bool t_ = av4 <= bv4; c4 = t_ ? av4 : bv4; ci4 = t_ ? ai4 : bi4; }
      PMAXV(av3, ai3, bv0, bi0, t, ti_); PMINA(t, ti_, c4, ci4);
      PMAXV(av2, ai2, bv1, bi1, t, ti_); PMINA(t, ti_, c4, ci4);
      PMAXV(av1, ai1, bv2, bi2, t, ti_); PMINA(t, ti_, c4, ci4);
      PMAXV(av0, ai0, bv3, bi3, t, ti_); PMINA(t, ti_, c4, ci4);
      av0 = c0; av1 = c1; av2 = c2; av3 = c3; av4 = c4;
      ai0 = ci0; ai1 = ci1; ai2 = ci2; ai3 = ci3; ai4 = ci4;
    }
    if (tid == 0)
      out[q] = 0.2f * (y[ai0] + y[ai1] + y[ai2] + y[ai3] + y[ai4]);
  }
}

// ---------------------------------------------------------------------------
extern "C" void kernel_launch(void* const* d_in, const int* in_sizes, int n_in,
                              void* d_out, int out_size, void* d_ws, size_t ws_size,
                              hipStream_t stream) {
  (void)in_sizes; (void)n_in; (void)out_size; (void)ws_size;
  const float* x  = (const float*)d_in[0];   // [4096,128]
  const float* xt = (const float*)d_in[1];   // [50000,128]
  const float* y  = (const float*)d_in[2];   // [50000,1]
  float* out = (float*)d_out;                // [4096,1]

  // workspace: tsq 200,704 B | pli u16 1,048,576 B = 1,249,280 B (proven safe R6)
  float*          tsq = (float*)d_ws;
  unsigned short* pli = (unsigned short*)((char*)d_ws + 200704);

  knn_tsq<<<dim3((NTRAIN + 31) / 32), dim3(256), 0, stream>>>(xt, tsq);
  knn_score<<<dim3(512), dim3(512), 0, stream>>>(x, xt, tsq, pli);
  knn_rescore<<<dim3(Q), dim3(256), 0, stream>>>(x, xt, tsq, pli, y, out);
}